// Round 1
// baseline (210.954 us; speedup 1.0000x reference)
//
#include <hip/hip_runtime.h>
#include <hip/hip_bf16.h>

typedef __attribute__((ext_vector_type(8))) short bf16x8;
typedef __attribute__((ext_vector_type(4))) float f32x4;

#define BM 128
#define KPAD 232   // 224 + 8 bf16 pad (row stride 464B -> 2-way LDS aliasing, free)
#define NPAD 264   // 256 + 8 bf16 pad

__device__ __forceinline__ short f2bf(float x) {
  __hip_bfloat16 h = __float2bfloat16(x);
  union { __hip_bfloat16 h; short s; } u; u.h = h; return u.s;
}

__device__ __forceinline__ void cvt4(short* d, float4 v) {
  short4 s;
  s.x = f2bf(v.x); s.y = f2bf(v.y); s.z = f2bf(v.z); s.w = f2bf(v.w);
  *reinterpret_cast<short4*>(d) = s;
}

// Transpose weights to K-major bf16 so MFMA B-fragments are 16B-contiguous loads.
// W1 [224][256] -> W1T [256][224];  W2 [256][64] -> W2T [64][256]
__global__ void prep_weights(const float* __restrict__ W1,
                             const float* __restrict__ W2,
                             short* __restrict__ W1T,
                             short* __restrict__ W2T) {
  int idx = blockIdx.x * 256 + threadIdx.x;
  if (idx < 224 * 256) {
    int k = idx >> 8, n = idx & 255;
    W1T[n * 224 + k] = f2bf(W1[idx]);
  } else {
    int i2 = idx - 224 * 256;
    if (i2 < 256 * 64) {
      int k = i2 >> 6, n = i2 & 63;
      W2T[n * 256 + k] = f2bf(W2[i2]);
    }
  }
}

__global__ __launch_bounds__(512, 4) void edge_mlp(
    const float* __restrict__ edges,
    const float* __restrict__ nodes,
    const float* __restrict__ glob,
    const int* __restrict__ recv,
    const int* __restrict__ send,
    const int* __restrict__ egi,
    const short* __restrict__ W1T,
    const short* __restrict__ W2T,
    const float* __restrict__ b1,
    const float* __restrict__ b2,
    float* __restrict__ out)
{
  // One buffer, two lives: X tile [128][KPAD] bf16, then H tile [128][NPAD] bf16.
  __shared__ short S[BM * NPAD];   // 67,584 B -> 2 blocks/CU

  const int t = threadIdx.x;
  const int e0 = blockIdx.x * BM;

  // ---- stage X = [edges | nodes[recv] | nodes[send] | globals] as bf16 ----
  {
    const int grp = t >> 7;    // wave-uniform role split (no intra-wave divergence)
    const int r = t & 127;
    if (grp == 0) {
      // fully coalesced: this block's 128 edge rows are contiguous
      const float* src = edges + (size_t)e0 * 64;
      #pragma unroll
      for (int it = 0; it < 16; ++it) {
        int f = it * 512 + r * 4;
        float4 v = *reinterpret_cast<const float4*>(src + f);
        cvt4(&S[(f >> 6) * KPAD + (f & 63)], v);
      }
    } else if (grp == 1) {
      const float* src = nodes + (size_t)recv[e0 + r] * 64;
      short* d = &S[r * KPAD + 64];
      #pragma unroll
      for (int c = 0; c < 64; c += 4)
        cvt4(d + c, *reinterpret_cast<const float4*>(src + c));
    } else if (grp == 2) {
      const float* src = nodes + (size_t)send[e0 + r] * 64;
      short* d = &S[r * KPAD + 128];
      #pragma unroll
      for (int c = 0; c < 64; c += 4)
        cvt4(d + c, *reinterpret_cast<const float4*>(src + c));
    } else {
      const float* src = glob + (size_t)egi[e0 + r] * 32;
      short* d = &S[r * KPAD + 192];
      #pragma unroll
      for (int c = 0; c < 32; c += 4)
        cvt4(d + c, *reinterpret_cast<const float4*>(src + c));
    }
  }
  __syncthreads();

  const int w = t >> 6;
  const int lane = t & 63;
  const int lrow = lane & 15;
  const int lk8 = (lane >> 4) * 8;

  // ---- layer 1: H = relu(X @ W1 + b1); wave w owns hidden cols [w*32, w*32+32) ----
  f32x4 acc[8][2];
  #pragma unroll
  for (int i = 0; i < 8; ++i) {
    acc[i][0] = f32x4{0.f, 0.f, 0.f, 0.f};
    acc[i][1] = f32x4{0.f, 0.f, 0.f, 0.f};
  }

  const int n0 = w * 32;
  const short* bp0 = W1T + (n0 + lrow) * 224 + lk8;
  const short* bp1 = bp0 + 16 * 224;

  bf16x8 nb0 = *reinterpret_cast<const bf16x8*>(bp0);
  bf16x8 nb1 = *reinterpret_cast<const bf16x8*>(bp1);
  #pragma unroll 1
  for (int k0 = 0; k0 < 224; k0 += 32) {
    bf16x8 b0 = nb0, b1f = nb1;
    if (k0 + 32 < 224) {   // register prefetch of next K-step's B-frags (L2-hot)
      nb0 = *reinterpret_cast<const bf16x8*>(bp0 + k0 + 32);
      nb1 = *reinterpret_cast<const bf16x8*>(bp1 + k0 + 32);
    }
    #pragma unroll
    for (int mi = 0; mi < 8; ++mi) {
      bf16x8 a = *reinterpret_cast<const bf16x8*>(&S[(mi * 16 + lrow) * KPAD + k0 + lk8]);
      acc[mi][0] = __builtin_amdgcn_mfma_f32_16x16x32_bf16(a, b0, acc[mi][0], 0, 0, 0);
      acc[mi][1] = __builtin_amdgcn_mfma_f32_16x16x32_bf16(a, b1f, acc[mi][1], 0, 0, 0);
    }
  }

  __syncthreads();   // all waves done reading X before S is reused for H

  {
    const float bias0 = b1[n0 + lrow];
    const float bias1 = b1[n0 + 16 + lrow];
    const int r4 = (lane >> 4) * 4;
    #pragma unroll
    for (int mi = 0; mi < 8; ++mi) {
      #pragma unroll
      for (int rr = 0; rr < 4; ++rr) {
        int row = mi * 16 + r4 + rr;
        float v0 = acc[mi][0][rr] + bias0;
        float v1 = acc[mi][1][rr] + bias1;
        S[row * NPAD + n0 + lrow]      = f2bf(v0 > 0.f ? v0 : 0.f);
        S[row * NPAD + n0 + 16 + lrow] = f2bf(v1 > 0.f ? v1 : 0.f);
      }
    }
  }
  __syncthreads();

  // ---- layer 2: O = H @ W2 + b2; wave w -> n-tile (w&3), m-tiles (w>>2)*4.. ----
  const int j2 = w & 3;
  const int mb = (w >> 2) * 4;
  f32x4 acc2[4];
  #pragma unroll
  for (int i = 0; i < 4; ++i) acc2[i] = f32x4{0.f, 0.f, 0.f, 0.f};

  const short* bp2 = W2T + (j2 * 16 + lrow) * 256 + lk8;
  bf16x8 nb2 = *reinterpret_cast<const bf16x8*>(bp2);
  #pragma unroll 1
  for (int k0 = 0; k0 < 256; k0 += 32) {
    bf16x8 b = nb2;
    if (k0 + 32 < 256) nb2 = *reinterpret_cast<const bf16x8*>(bp2 + k0 + 32);
    #pragma unroll
    for (int mi = 0; mi < 4; ++mi) {
      bf16x8 a = *reinterpret_cast<const bf16x8*>(&S[((mb + mi) * 16 + lrow) * NPAD + k0 + lk8]);
      acc2[mi] = __builtin_amdgcn_mfma_f32_16x16x32_bf16(a, b, acc2[mi], 0, 0, 0);
    }
  }

  {
    const int ocol = j2 * 16 + lrow;
    const float bias = b2[ocol];
    const int r4 = (lane >> 4) * 4;
    #pragma unroll
    for (int mi = 0; mi < 4; ++mi) {
      #pragma unroll
      for (int rr = 0; rr < 4; ++rr) {
        int row = (mb + mi) * 16 + r4 + rr;
        out[(size_t)(e0 + row) * 64 + ocol] = acc2[mi][rr] + bias;
      }
    }
  }
}

extern "C" void kernel_launch(void* const* d_in, const int* in_sizes, int n_in,
                              void* d_out, int out_size, void* d_ws, size_t ws_size,
                              hipStream_t stream) {
  (void)in_sizes; (void)n_in; (void)out_size; (void)ws_size;
  const float* edges = (const float*)d_in[0];
  const float* nodes = (const float*)d_in[1];
  const float* glob  = (const float*)d_in[2];
  const int*   recv  = (const int*)d_in[3];
  const int*   send  = (const int*)d_in[4];
  const int*   egi   = (const int*)d_in[5];
  const float* W1    = (const float*)d_in[6];
  const float* b1    = (const float*)d_in[7];
  const float* W2    = (const float*)d_in[8];
  const float* b2    = (const float*)d_in[9];
  float* out = (float*)d_out;

  short* W1T = (short*)d_ws;            // 256*224 bf16 = 114,688 B
  short* W2T = W1T + 256 * 224;         // 64*256 bf16  =  32,768 B

  prep_weights<<<288, 256, 0, stream>>>(W1, W2, W1T, W2T);
  edge_mlp<<<800000 / BM, 512, 0, stream>>>(edges, nodes, glob, recv, send, egi,
                                            W1T, W2T, b1, b2, out);
}